// Round 3
// baseline (125.800 us; speedup 1.0000x reference)
//
#include <hip/hip_runtime.h>

// ---------------------------------------------------------------------------
// relu-attention block (B=2, Ci=128, Co=64, N=4096):
//   theta/phi/psi = 1x1conv(z); g = phi^T psi; P = relu(g/N);
//   tmp = P theta^T; out = w_v tmp + b_v + z.
// K1: projections -> Q(phi)[b][n][64], K(psi)[b][n][64], V(theta^T)[b][o][n] bf16
// K2: fused attention, P kept in REGISTERS via swapped QK^T (S^T = mfma(K,Q))
//     whose D-layout matches the 16x16x16 MFMA B-fragment (k = lg*4+j).
// ---------------------------------------------------------------------------

#define NSEQ 4096
#define CI 128
#define CO 64

typedef __attribute__((ext_vector_type(8))) short bf16x8;   // 8 bf16 = 4 VGPR
typedef __attribute__((ext_vector_type(4))) short bf16x4;   // 4 bf16 = 2 VGPR
typedef __attribute__((ext_vector_type(4))) float f32x4;

static __device__ inline short f2bf(float f) {
  union { float f; unsigned u; } v; v.f = f;
  unsigned r = v.u + 0x7fffu + ((v.u >> 16) & 1u);   // RNE
  return (short)(r >> 16);
}

#define MFMA32(a, b, c) __builtin_amdgcn_mfma_f32_16x16x32_bf16(a, b, c, 0, 0, 0)

#if __has_builtin(__builtin_amdgcn_mfma_f32_16x16x16bf16_1k)
static __device__ inline f32x4 mfma16(bf16x4 a, bf16x4 b, f32x4 c) {
  return __builtin_amdgcn_mfma_f32_16x16x16bf16_1k(a, b, c, 0, 0, 0);
}
#else
static __device__ inline f32x4 mfma16(bf16x4 a, bf16x4 b, f32x4 c) {
  asm("v_mfma_f32_16x16x16_bf16 %0, %1, %2, %0" : "+v"(c) : "v"(a), "v"(b));
  return c;
}
#endif

// ---------------------------------------------------------------------------
// Kernel 1: projections. grid = B * (N/64) = 128 WGs, 256 threads.
// Wave w owns o-block [w*16, w*16+16) for Q/K (W as A-operand -> packed b64
// stores along o) and n-block [w*16,..) for V (packed b64 stores along n).
// ---------------------------------------------------------------------------
__global__ __launch_bounds__(256, 1) void proj_kernel(
    const float* __restrict__ z,
    const float* __restrict__ w_th, const float* __restrict__ b_th,
    const float* __restrict__ w_ph, const float* __restrict__ b_ph,
    const float* __restrict__ w_ps, const float* __restrict__ b_ps,
    short* __restrict__ Qg, short* __restrict__ Kg, short* __restrict__ Vt)
{
  __shared__ f32x4 zt4[16384 / 16];        // z^T tile [64 n][128 c] bf16, swizzled
  char* zt = (char*)zt4;

  const int wgid = blockIdx.x;
  const int b = wgid >> 6;
  const int n0 = (wgid & 63) * 64;
  const int t = threadIdx.x;

  // ---- stage z^T tile (transpose fp32 [c][n] -> bf16 LDS [n][c], swizzled) ----
  {
    const int ck = t & 15;
    const int cr = t >> 4;
#pragma unroll
    for (int g = 0; g < 8; ++g) {
      const int c = g * 16 + cr;
      f32x4 v = *(const f32x4*)(z + (size_t)(b * CI + c) * NSEQ + n0 + ck * 4);
#pragma unroll
      for (int i = 0; i < 4; ++i) {
        const int n = ck * 4 + i;
        const int chunk = (c >> 3) ^ (n & 7);
        *(short*)(zt + n * 256 + chunk * 16 + (c & 7) * 2) = f2bf(v[i]);
      }
    }
  }
  __syncthreads();

  const int w = t >> 6, l = t & 63, lr = l & 15, lg = l >> 4;
  const f32x4 zero4 = {0.f, 0.f, 0.f, 0.f};

  // z^T fragments for ALL 4 n-blocks (serve as A- or B-operands; same layout)
  bf16x8 zf[4][4];
#pragma unroll
  for (int nsub = 0; nsub < 4; ++nsub) {
#pragma unroll
    for (int ks = 0; ks < 4; ++ks) {
      const int n = nsub * 16 + lr;
      const int chunk = (ks * 4 + lg) ^ (n & 7);
      zf[nsub][ks] = *(const bf16x8*)(zt + n * 256 + chunk * 16);
    }
  }

  // ---- mats Q (phi), K (psi): D[o][n] = W · z^T, wave owns o-block w ----
  {
    const float* Wm[2]   = {w_ph, w_ps};
    const float* Bm[2]   = {b_ph, b_ps};
    short*       Dm[2]   = {Qg, Kg};
#pragma unroll
    for (int mt = 0; mt < 2; ++mt) {
      bf16x8 wf[4];
#pragma unroll
      for (int ks = 0; ks < 4; ++ks) {
        const float* wp = Wm[mt] + (w * 16 + lr) * CI + ks * 32 + lg * 8;
        f32x4 x0 = *(const f32x4*)wp;
        f32x4 x1 = *(const f32x4*)(wp + 4);
#pragma unroll
        for (int j = 0; j < 4; ++j) { wf[ks][j] = f2bf(x0[j]); wf[ks][4 + j] = f2bf(x1[j]); }
      }
      const f32x4 bias4 = *(const f32x4*)(Bm[mt] + w * 16 + lg * 4);
#pragma unroll
      for (int nsub = 0; nsub < 4; ++nsub) {
        f32x4 acc = zero4;
#pragma unroll
        for (int ks = 0; ks < 4; ++ks)
          acc = MFMA32(wf[ks], zf[nsub][ks], acc);
        // D: col = n = lr, row = o = w*16 + lg*4 + r  -> pack 4 consecutive o
        bf16x4 pk;
#pragma unroll
        for (int r = 0; r < 4; ++r) pk[r] = f2bf(acc[r] + bias4[r]);
        *(bf16x4*)(Dm[mt] + (size_t)(b * NSEQ + n0 + nsub * 16 + lr) * CO + w * 16 + lg * 4) = pk;
      }
    }
  }

  // ---- mat V (theta^T): D[n][o] = z^T · W^T, wave owns n-block w ----
#pragma unroll
  for (int osub = 0; osub < 4; ++osub) {
    f32x4 acc = zero4;
#pragma unroll
    for (int ks = 0; ks < 4; ++ks) {
      const float* wp = w_th + (osub * 16 + lr) * CI + ks * 32 + lg * 8;
      f32x4 x0 = *(const f32x4*)wp;
      f32x4 x1 = *(const f32x4*)(wp + 4);
      bf16x8 wtf;
#pragma unroll
      for (int j = 0; j < 4; ++j) { wtf[j] = f2bf(x0[j]); wtf[4 + j] = f2bf(x1[j]); }
      acc = MFMA32(zf[w][ks], wtf, acc);
    }
    const int o = osub * 16 + lr;
    const float bias = b_th[o];
    // D: col = o = lr, row = n = w*16 + lg*4 + r -> pack 4 consecutive n
    bf16x4 pk;
#pragma unroll
    for (int r = 0; r < 4; ++r) pk[r] = f2bf(acc[r] + bias);
    *(bf16x4*)(Vt + (size_t)(b * CO + o) * NSEQ + n0 + w * 16 + lg * 4) = pk;
  }
}

// ---------------------------------------------------------------------------
// Kernel 2: fused relu-attention + projection + residual.
// grid = B * (N/32) = 256 WGs, 256 threads (4 waves).
// Waves 0,1: n rows 0-15/16-31, m-parity 0; waves 2,3: same rows, parity 1.
// Per superstep (128 m): S^T = mfma32(K,Q) -> P in regs -> O^T += mfma16(V,P).
// LDS: K[128][64] 16KB + V[64][128] 16KB = 32KB, XOR-swizzled 16B chunks.
// ---------------------------------------------------------------------------
__global__ __launch_bounds__(256, 1) void attn_kernel(
    const short* __restrict__ Qg, const short* __restrict__ Kg,
    const short* __restrict__ Vt, const float* __restrict__ w_v,
    const float* __restrict__ b_v, const float* __restrict__ z,
    float* __restrict__ out)
{
  __shared__ f32x4 smem4[32768 / 16];
  char* smem = (char*)smem4;
  char* Km = smem;             // [128 m][64 c] bf16, 8 chunks/row, ^ (m&7)
  char* Vm = smem + 16384;     // [64 o][128 m] bf16, 16 chunks/row, ^ (o&7)

  const int wg = blockIdx.x;
  const int b = wg >> 7;
  const int n0 = (wg & 127) * 32;
  const int t = threadIdx.x;
  const int w = t >> 6, l = t & 63, lr = l & 15, lg = l >> 4;
  const int tw = w >> 1;                 // m-parity this wave owns
  const int nbase = n0 + (w & 1) * 16;   // wave's 16 Q rows
  const f32x4 zero4 = {0.f, 0.f, 0.f, 0.f};

  // Q B-fragments (col = n = lr, k = c): persistent
  bf16x8 q0, q1;
  {
    const short* qp = Qg + (size_t)(b * NSEQ + nbase + lr) * CO + lg * 8;
    q0 = *(const bf16x8*)qp;
    q1 = *(const bf16x8*)(qp + 32);
  }

  f32x4 oacc[4];
#pragma unroll
  for (int i = 0; i < 4; ++i) oacc[i] = zero4;

  bf16x8 stg[8];
  auto load_stage = [&](int ss) {
    const int m0 = ss * 128;
#pragma unroll
    for (int r = 0; r < 4; ++r) {                  // K: 1024 chunks
      const int ck = r * 256 + t;
      stg[r] = *(const bf16x8*)(Kg + (size_t)(b * NSEQ + m0 + (ck >> 3)) * CO + (ck & 7) * 8);
    }
#pragma unroll
    for (int r = 0; r < 4; ++r) {                  // V: 1024 chunks
      const int cv = r * 256 + t;
      stg[4 + r] = *(const bf16x8*)(Vt + (size_t)(b * CO + (cv >> 4)) * NSEQ + m0 + (cv & 15) * 8);
    }
  };
  auto write_stage = [&]() {
#pragma unroll
    for (int r = 0; r < 4; ++r) {
      const int ck = r * 256 + t, m = ck >> 3, c8 = ck & 7;
      *(bf16x8*)(Km + m * 128 + ((c8 ^ (m & 7)) * 16)) = stg[r];
    }
#pragma unroll
    for (int r = 0; r < 4; ++r) {
      const int cv = r * 256 + t, o = cv >> 4, mc = cv & 15;
      *(bf16x8*)(Vm + o * 256 + ((mc ^ (o & 7)) * 16)) = stg[4 + r];
    }
  };

  load_stage(0);
  write_stage();
  __syncthreads();

  for (int ss = 0; ss < 32; ++ss) {
    if (ss < 31) load_stage(ss + 1);     // global loads fly during compute (T14)

#pragma unroll
    for (int msub = 0; msub < 4; ++msub) {
      // ---- S^T = K · Q^T over c (A = K: row=m=lr, k=c) ----
      const int mr = tw * 64 + msub * 16 + lr;
      bf16x8 k0 = *(const bf16x8*)(Km + mr * 128 + ((lg ^ (mr & 7)) * 16));
      bf16x8 k1 = *(const bf16x8*)(Km + mr * 128 + (((4 + lg) ^ (mr & 7)) * 16));
      f32x4 s = MFMA32(k0, q0, zero4);
      s = MFMA32(k1, q1, s);
      // D: col=n=lr, row = m_local = lg*4+r  ==  B-frag layout of mfma16 (k=lg*4+j)
      bf16x4 pf;
#pragma unroll
      for (int r = 0; r < 4; ++r) {
        const float p = s[r] > 0.f ? s[r] * (1.f / 4096.f) : 0.f;
        pf[r] = f2bf(p);
      }
      // ---- O^T += V · P^T (K=16 per msub) ----
      const int vchunk = tw * 8 + msub * 2 + (lg >> 1);
      const int voff = (lg & 1) * 8;
#pragma unroll
      for (int osub = 0; osub < 4; ++osub) {
        const int orow = osub * 16 + lr;
        bf16x4 vf = *(const bf16x4*)(Vm + orow * 256 + ((vchunk ^ (orow & 7)) * 16) + voff);
        oacc[osub] = mfma16(vf, pf, oacc[osub]);
      }
    }

    __syncthreads();                     // all reads of current tiles done
    if (ss < 31) {
      write_stage();
      __syncthreads();
    }
  }

  // ---- reduce wave pairs (0,2) and (1,3) through LDS ----
  // oacc[osub][r] = O^T[o = osub*16 + lg*4 + r][n = nbase + lr]
  float* red = (float*)smem;             // 2 x [64 o][16 n] f32 = 8KB (reuse Km)
  if (tw == 1) {
    float* dst = red + (w & 1) * 1024;
#pragma unroll
    for (int osub = 0; osub < 4; ++osub)
#pragma unroll
      for (int r = 0; r < 4; ++r)
        dst[(osub * 16 + lg * 4 + r) * 16 + lr] = oacc[osub][r];
  }
  __syncthreads();

  if (tw == 0) {
    const float* sp = red + (w & 1) * 1024;
    bf16x4 of[4];                         // O^T frags (B-operand of mfma16)
#pragma unroll
    for (int osub = 0; osub < 4; ++osub) {
#pragma unroll
      for (int r = 0; r < 4; ++r) {
        const float v = oacc[osub][r] + sp[(osub * 16 + lg * 4 + r) * 16 + lr];
        of[osub][r] = f2bf(v);
      }
    }
    // epilogue: out[ci][n] = sum_o w_v[ci][o] O^T[o][n] + b_v[ci] + z
#pragma unroll
    for (int cis = 0; cis < 8; ++cis) {
      f32x4 e = zero4;
#pragma unroll
      for (int osub = 0; osub < 4; ++osub) {
        f32x4 wl = *(const f32x4*)(w_v + (cis * 16 + lr) * CO + osub * 16 + lg * 4);
        bf16x4 wf;
#pragma unroll
        for (int j = 0; j < 4; ++j) wf[j] = f2bf(wl[j]);
        e = mfma16(wf, of[osub], e);
      }
      const f32x4 bv = *(const f32x4*)(b_v + cis * 16 + lg * 4);
#pragma unroll
      for (int r = 0; r < 4; ++r) {
        const int ci = cis * 16 + lg * 4 + r;
        const size_t off = (size_t)(b * CI + ci) * NSEQ + nbase + lr;
        out[off] = e[r] + z[off] + bv[r];   // 16 consecutive n per quarter-wave
      }
    }
  }
}

// ---------------------------------------------------------------------------
extern "C" void kernel_launch(void* const* d_in, const int* in_sizes, int n_in,
                              void* d_out, int out_size, void* d_ws, size_t ws_size,
                              hipStream_t stream) {
  const float* z    = (const float*)d_in[0];
  const float* w_th = (const float*)d_in[1];
  const float* b_th = (const float*)d_in[2];
  const float* w_ph = (const float*)d_in[3];
  const float* b_ph = (const float*)d_in[4];
  const float* w_ps = (const float*)d_in[5];
  const float* b_ps = (const float*)d_in[6];
  const float* w_v  = (const float*)d_in[7];
  const float* b_v  = (const float*)d_in[8];
  float* out = (float*)d_out;

  short* Qg = (short*)d_ws;                       // [2][4096][64] bf16 = 1 MB
  short* Kg = Qg + 2 * NSEQ * CO;                 // [2][4096][64] bf16 = 1 MB
  short* Vt = Kg + 2 * NSEQ * CO;                 // [2][64][4096] bf16 = 1 MB

  proj_kernel<<<128, 256, 0, stream>>>(z, w_th, b_th, w_ph, b_ph, w_ps, b_ps,
                                       Qg, Kg, Vt);
  attn_kernel<<<256, 256, 0, stream>>>(Qg, Kg, Vt, w_v, b_v, z, out);
}

// Round 4
// 105.761 us; speedup vs baseline: 1.1895x; 1.1895x over previous
//
#include <hip/hip_runtime.h>

// ---------------------------------------------------------------------------
// relu-attention block (B=2, Ci=128, Co=64, N=4096):
//   theta/phi/psi = 1x1conv(z); g = phi^T psi; P = relu(g/N);
//   tmp = P theta^T; out = w_v tmp + b_v + z.
// K1 proj: Q(phi)[b][n][64], K(psi)[b][n][64], V(theta^T)[b][o][n] bf16 (no LDS)
// K2 attn: grid B*128nt*4msplit; waves own m-quarters; partial O -> ws (f32)
// K3 epi:  sum 4 partials, w_v projection via mfma16, + bias + z residual
// ---------------------------------------------------------------------------

#define NSEQ 4096
#define CI 128
#define CO 64

typedef __attribute__((ext_vector_type(8))) short bf16x8;   // 8 bf16 = 4 VGPR
typedef __attribute__((ext_vector_type(4))) short bf16x4;   // 4 bf16 = 2 VGPR
typedef __attribute__((ext_vector_type(4))) float f32x4;

static __device__ inline short f2bf(float f) {
  union { float f; unsigned u; } v; v.f = f;
  unsigned r = v.u + 0x7fffu + ((v.u >> 16) & 1u);   // RNE
  return (short)(r >> 16);
}

#define MFMA32(a, b, c) __builtin_amdgcn_mfma_f32_16x16x32_bf16(a, b, c, 0, 0, 0)

#if __has_builtin(__builtin_amdgcn_mfma_f32_16x16x16bf16_1k)
static __device__ inline f32x4 mfma16(bf16x4 a, bf16x4 b, f32x4 c) {
  return __builtin_amdgcn_mfma_f32_16x16x16bf16_1k(a, b, c, 0, 0, 0);
}
#else
static __device__ inline f32x4 mfma16(bf16x4 a, bf16x4 b, f32x4 c) {
  asm("v_mfma_f32_16x16x16_bf16 %0, %1, %2, %0" : "+v"(c) : "v"(a), "v"(b));
  return c;
}
#endif

// ---------------------------------------------------------------------------
// Kernel 1: projections. grid = B * (N/16) = 512 WGs, 256 threads, no LDS.
// Wave w: Q/K o-block w (W as A-operand), V o-block w (W^T as B-operand).
// z fragments gathered directly from global (64B-sector friendly, L2-hot).
// ---------------------------------------------------------------------------
__global__ __launch_bounds__(256, 2) void proj_kernel(
    const float* __restrict__ z,
    const float* __restrict__ w_th, const float* __restrict__ b_th,
    const float* __restrict__ w_ph, const float* __restrict__ b_ph,
    const float* __restrict__ w_ps, const float* __restrict__ b_ps,
    short* __restrict__ Qg, short* __restrict__ Kg, short* __restrict__ Vt)
{
  const int bid = blockIdx.x;
  const int b = bid >> 8;
  const int n0 = (bid & 255) * 16;
  const int t = threadIdx.x;
  const int w = t >> 6, l = t & 63, lr = l & 15, lg = l >> 4;
  const f32x4 zero4 = {0.f, 0.f, 0.f, 0.f};

  // ---- z fragments: zf[ks][j] = z[c = ks*32+lg*8+j][n0+lr] (A- and B-frag) ----
  bf16x8 zf[4];
#pragma unroll
  for (int ks = 0; ks < 4; ++ks) {
    const float* zp = z + (size_t)(b * CI + ks * 32 + lg * 8) * NSEQ + n0 + lr;
    float tmp[8];
#pragma unroll
    for (int j = 0; j < 8; ++j) tmp[j] = zp[(size_t)j * NSEQ];
#pragma unroll
    for (int j = 0; j < 8; ++j) zf[ks][j] = f2bf(tmp[j]);
  }

  // ---- Q (phi), K (psi): D[o = w*16 + lg*4 + r][n = n0 + lr] ----
  {
    const float* Wm[2] = {w_ph, w_ps};
    const float* Bm[2] = {b_ph, b_ps};
    short*       Dm[2] = {Qg, Kg};
#pragma unroll
    for (int mt = 0; mt < 2; ++mt) {
      f32x4 acc = zero4;
#pragma unroll
      for (int ks = 0; ks < 4; ++ks) {
        const float* wp = Wm[mt] + (size_t)(w * 16 + lr) * CI + ks * 32 + lg * 8;
        f32x4 x0 = *(const f32x4*)wp;
        f32x4 x1 = *(const f32x4*)(wp + 4);
        bf16x8 wf;
#pragma unroll
        for (int j = 0; j < 4; ++j) { wf[j] = f2bf(x0[j]); wf[4 + j] = f2bf(x1[j]); }
        acc = MFMA32(wf, zf[ks], acc);
      }
      const f32x4 bias4 = *(const f32x4*)(Bm[mt] + w * 16 + lg * 4);
      bf16x4 pk;
#pragma unroll
      for (int r = 0; r < 4; ++r) pk[r] = f2bf(acc[r] + bias4[r]);
      *(bf16x4*)(Dm[mt] + (size_t)(b * NSEQ + n0 + lr) * CO + w * 16 + lg * 4) = pk;
    }
  }

  // ---- V (theta^T): D[n = n0 + lg*4 + r][o = w*16 + lr] ----
  {
    f32x4 acc = zero4;
#pragma unroll
    for (int ks = 0; ks < 4; ++ks) {
      const float* wp = w_th + (size_t)(w * 16 + lr) * CI + ks * 32 + lg * 8;
      f32x4 x0 = *(const f32x4*)wp;
      f32x4 x1 = *(const f32x4*)(wp + 4);
      bf16x8 wtf;
#pragma unroll
      for (int j = 0; j < 4; ++j) { wtf[j] = f2bf(x0[j]); wtf[4 + j] = f2bf(x1[j]); }
      acc = MFMA32(zf[ks], wtf, acc);
    }
    const float bias = b_th[w * 16 + lr];
    bf16x4 pk;
#pragma unroll
    for (int r = 0; r < 4; ++r) pk[r] = f2bf(acc[r] + bias);
    *(bf16x4*)(Vt + (size_t)(b * CO + w * 16 + lr) * NSEQ + n0 + lg * 4) = pk;
  }
}

// ---------------------------------------------------------------------------
// Kernel 2: fused relu-attention, partial over m. grid = 1024 WGs, 256 thr.
// blockIdx&7 -> (b, msplit) group (XCD-local K/V slice); blockIdx>>3 -> n-tile.
// Wave w owns m-quarter [w*32, w*32+32) of each 128-m superstep, ALL 32 n.
// Per (msub, nsub): S^T = mfma32(K,Q); P in regs; O^T += mfma16(V, P).
// LDS: K[128][64] 16KB + V[64][128] 16KB = 32KB, XOR-swizzled 16B chunks.
// ---------------------------------------------------------------------------
__global__ __launch_bounds__(256, 4) void attn_kernel(
    const short* __restrict__ Qg, const short* __restrict__ Kg,
    const short* __restrict__ Vt, float* __restrict__ Opart)
{
  __shared__ f32x4 smem4[32768 / 16];
  char* smem = (char*)smem4;
  char* Km = smem;             // [128 m][64 c] bf16, 8 chunks/row, ^ (m&7)
  char* Vm = smem + 16384;     // [64 o][128 m] bf16, 16 chunks/row, ^ (o&7)

  const int bid = blockIdx.x;
  const int grp = bid & 7;               // ~XCD id under round-robin dispatch
  const int nt = bid >> 3;               // 0..127
  const int b = grp >> 2, msi = grp & 3;
  const int n0 = nt * 32;
  const int m_base = msi * 1024;
  const int t = threadIdx.x;
  const int w = t >> 6, l = t & 63, lr = l & 15, lg = l >> 4;
  const f32x4 zero4 = {0.f, 0.f, 0.f, 0.f};

  // Q B-fragments for both 16-n halves (col = n = lr, k = c)
  bf16x8 q[2][2];
#pragma unroll
  for (int nsub = 0; nsub < 2; ++nsub) {
    const short* qp = Qg + (size_t)(b * NSEQ + n0 + nsub * 16 + lr) * CO + lg * 8;
    q[nsub][0] = *(const bf16x8*)qp;
    q[nsub][1] = *(const bf16x8*)(qp + 32);
  }

  f32x4 oacc[4][2];
#pragma unroll
  for (int i = 0; i < 4; ++i)
#pragma unroll
    for (int j = 0; j < 2; ++j) oacc[i][j] = zero4;

  bf16x8 stg[8];
  auto load_stage = [&](int ss) {
    const int m0 = m_base + ss * 128;
#pragma unroll
    for (int r = 0; r < 4; ++r) {                  // K: 1024 chunks
      const int ck = r * 256 + t;
      stg[r] = *(const bf16x8*)(Kg + (size_t)(b * NSEQ + m0 + (ck >> 3)) * CO + (ck & 7) * 8);
    }
#pragma unroll
    for (int r = 0; r < 4; ++r) {                  // V: 1024 chunks
      const int cv = r * 256 + t;
      stg[4 + r] = *(const bf16x8*)(Vt + (size_t)(b * CO + (cv >> 4)) * NSEQ + m0 + (cv & 15) * 8);
    }
  };
  auto write_stage = [&]() {
#pragma unroll
    for (int r = 0; r < 4; ++r) {
      const int ck = r * 256 + t, m = ck >> 3, c8 = ck & 7;
      *(bf16x8*)(Km + m * 128 + ((c8 ^ (m & 7)) * 16)) = stg[r];
    }
#pragma unroll
    for (int r = 0; r < 4; ++r) {
      const int cv = r * 256 + t, o = cv >> 4, mc = cv & 15;
      *(bf16x8*)(Vm + o * 256 + ((mc ^ (o & 7)) * 16)) = stg[4 + r];
    }
  };

  load_stage(0);
  write_stage();
  __syncthreads();

  for (int ss = 0; ss < 8; ++ss) {
    if (ss < 7) load_stage(ss + 1);      // next tile's loads fly during compute

#pragma unroll
    for (int msub = 0; msub < 2; ++msub) {
      const int mr = w * 32 + msub * 16 + lr;
      bf16x8 k0 = *(const bf16x8*)(Km + mr * 128 + ((lg ^ (mr & 7)) * 16));
      bf16x8 k1 = *(const bf16x8*)(Km + mr * 128 + (((4 + lg) ^ (mr & 7)) * 16));
      bf16x4 pf[2];
#pragma unroll
      for (int nsub = 0; nsub < 2; ++nsub) {
        f32x4 s = MFMA32(k0, q[nsub][0], zero4);
        s = MFMA32(k1, q[nsub][1], s);
        // D col = n = lr, row = m_local = lg*4+r == mfma16 B-frag k-slot
#pragma unroll
        for (int r = 0; r < 4; ++r) {
          const float p = s[r] > 0.f ? s[r] * (1.f / 4096.f) : 0.f;
          pf[nsub][r] = f2bf(p);
        }
      }
      const int vchunk = w * 4 + msub * 2 + (lg >> 1);
      const int voff = (lg & 1) * 8;
#pragma unroll
      for (int osub = 0; osub < 4; ++osub) {
        const int orow = osub * 16 + lr;
        bf16x4 vf = *(const bf16x4*)(Vm + orow * 256 + ((vchunk ^ (orow & 7)) * 16) + voff);
        oacc[osub][0] = mfma16(vf, pf[0], oacc[osub][0]);
        oacc[osub][1] = mfma16(vf, pf[1], oacc[osub][1]);
      }
    }

    __syncthreads();                     // all reads of current tiles done
    if (ss < 7) {
      write_stage();
      __syncthreads();
    }
  }

  // ---- in-WG reduce of 4 wave m-quarters, then partial store ----
  // oacc[osub][nsub][r] = O^T[o = osub*16+lg*4+r][n = nsub*16+lr]
  float* part = (float*)smem;            // 4 x [64 o][32 n] f32 = 32 KB
  {
    float* dst = part + w * 2048;
#pragma unroll
    for (int osub = 0; osub < 4; ++osub)
#pragma unroll
      for (int nsub = 0; nsub < 2; ++nsub)
#pragma unroll
        for (int r = 0; r < 4; ++r)
          dst[(osub * 16 + lg * 4 + r) * 32 + nsub * 16 + lr] = oacc[osub][nsub][r];
  }
  __syncthreads();
  {
    float* gout = Opart + (((size_t)(b * 128 + nt) * 4 + msi) * 2048);
#pragma unroll
    for (int pass = 0; pass < 2; ++pass) {
      const int o = w * 16 + pass * 8 + (l >> 3);
      const int nq = (l & 7) * 4;
      f32x4 s = *(const f32x4*)(part + o * 32 + nq);
#pragma unroll
      for (int p = 1; p < 4; ++p)
        s += *(const f32x4*)(part + p * 2048 + o * 32 + nq);
      *(f32x4*)(gout + o * 32 + nq) = s;
    }
  }
}

// ---------------------------------------------------------------------------
// Kernel 3: sum msplit partials, project with w_v (mfma16), + bias + z.
// grid = B * (N/16) = 512 WGs, 256 threads.
// ---------------------------------------------------------------------------
__global__ __launch_bounds__(256, 2) void epi_kernel(
    const float* __restrict__ Opart, const float* __restrict__ w_v,
    const float* __restrict__ b_v, const float* __restrict__ z,
    float* __restrict__ out)
{
  __shared__ float Olds[64 * 16];        // summed O^T [64 o][16 n] f32 = 4 KB

  const int bid = blockIdx.x;
  const int b = bid >> 8;
  const int n16 = bid & 255;
  const int n0 = n16 * 16;
  const int t = threadIdx.x;

  // sum 4 partials -> LDS
  {
    const float* src = Opart + ((size_t)(b * 128 + (n16 >> 1)) * 4) * 2048 + (n16 & 1) * 16;
    const int o = t >> 2, nq = (t & 3) * 4;
    f32x4 s = *(const f32x4*)(src + o * 32 + nq);
#pragma unroll
    for (int p = 1; p < 4; ++p)
      s += *(const f32x4*)(src + (size_t)p * 2048 + o * 32 + nq);
    *(f32x4*)(Olds + o * 16 + nq) = s;
  }
  __syncthreads();

  const int w = t >> 6, l = t & 63, lr = l & 15, lg = l >> 4;
  const f32x4 zero4 = {0.f, 0.f, 0.f, 0.f};

  // O^T B-frags: of[osub][j] = O[osub*16 + lg*4 + j][n0 + lr]
  bf16x4 of[4];
#pragma unroll
  for (int osub = 0; osub < 4; ++osub)
#pragma unroll
    for (int j = 0; j < 4; ++j)
      of[osub][j] = f2bf(Olds[(osub * 16 + lg * 4 + j) * 16 + lr]);

  // wave w handles ci groups {w*2, w*2+1} (32 ci rows)
#pragma unroll
  for (int c2 = 0; c2 < 2; ++c2) {
    const int cis = w * 2 + c2;
    f32x4 e = zero4;
#pragma unroll
    for (int osub = 0; osub < 4; ++osub) {
      f32x4 wl = *(const f32x4*)(w_v + (size_t)(cis * 16 + lr) * CO + osub * 16 + lg * 4);
      bf16x4 wf;
#pragma unroll
      for (int j = 0; j < 4; ++j) wf[j] = f2bf(wl[j]);
      e = mfma16(wf, of[osub], e);
    }
    const f32x4 bv = *(const f32x4*)(b_v + cis * 16 + lg * 4);
#pragma unroll
    for (int r = 0; r < 4; ++r) {
      const int ci = cis * 16 + lg * 4 + r;
      const size_t off = (size_t)(b * CI + ci) * NSEQ + n0 + lr;
      out[off] = e[r] + z[off] + bv[r];
    }
  }
}

// ---------------------------------------------------------------------------
extern "C" void kernel_launch(void* const* d_in, const int* in_sizes, int n_in,
                              void* d_out, int out_size, void* d_ws, size_t ws_size,
                              hipStream_t stream) {
  const float* z    = (const float*)d_in[0];
  const float* w_th = (const float*)d_in[1];
  const float* b_th = (const float*)d_in[2];
  const float* w_ph = (const float*)d_in[3];
  const float* b_ph = (const float*)d_in[4];
  const float* w_ps = (const float*)d_in[5];
  const float* b_ps = (const float*)d_in[6];
  const float* w_v  = (const float*)d_in[7];
  const float* b_v  = (const float*)d_in[8];
  float* out = (float*)d_out;

  short* Qg = (short*)d_ws;                       // [2][4096][64] bf16 = 1 MB
  short* Kg = Qg + 2 * NSEQ * CO;                 // [2][4096][64] bf16 = 1 MB
  short* Vt = Kg + 2 * NSEQ * CO;                 // [2][64][4096] bf16 = 1 MB
  float* Opart = (float*)((char*)d_ws + 3u * 1024 * 1024);  // [2][128][4][64][32] f32 = 8 MB

  proj_kernel<<<512, 256, 0, stream>>>(z, w_th, b_th, w_ph, b_ph, w_ps, b_ps,
                                       Qg, Kg, Vt);
  attn_kernel<<<1024, 256, 0, stream>>>(Qg, Kg, Vt, Opart);
  epi_kernel<<<512, 256, 0, stream>>>(Opart, w_v, b_v, z, out);
}